// Round 2
// baseline (1590.726 us; speedup 1.0000x reference)
//
#include <hip/hip_runtime.h>
#include <math.h>

#define N_NODES 32768
#define E_EDGES 524288
#define HIDDEN  256
#define NPG     512
#define NGRAPH  64
#define NHEAD   8
#define CDIM    32

typedef unsigned short bf16;

// ---------------- bf16 helpers (manual, RNE) ----------------
__device__ inline float bf2f(unsigned short u) {
    union { unsigned int i; float f; } v; v.i = ((unsigned int)u) << 16; return v.f;
}
__device__ inline unsigned short f2bf(float f) {
    union { float f; unsigned int i; } v; v.f = f;
    unsigned int x = v.i;
    return (unsigned short)((x + 0x7FFFu + ((x >> 16) & 1u)) >> 16);
}
__device__ inline float4 load4(const float* p) { return *(const float4*)p; }
__device__ inline float4 load4(const bf16* p) {
    ushort4 u = *(const ushort4*)p;
    return make_float4(bf2f(u.x), bf2f(u.y), bf2f(u.z), bf2f(u.w));
}
__device__ inline void store4(float* p, float4 v) { *(float4*)p = v; }
__device__ inline void store4(bf16* p, float4 v) {
    ushort4 u; u.x = f2bf(v.x); u.y = f2bf(v.y); u.z = f2bf(v.z); u.w = f2bf(v.w);
    *(ushort4*)p = u;
}

// ---------------- workspace layout (BYTE offsets) ----------------
// [0, 3.0M)   : graph prep (deg, ea, fill, row_ptr, col)
// [4Mi,52Mi)  : qkv bf16          -> later xl [4,20) + combined [4,20)
// [52Mi,68Mi) : attnout bf16
// [68Mi,84Mi) : gout bf16
// [20Mi,36Mi) : xr bf16           -> later part of h1
// [36Mi,52Mi) : localout bf16     -> later part of h1
// [20Mi,84Mi) : h1 bf16
// [84Mi,100Mi): ffn bf16
// peak = 100 MiB

// ---------------- small utility kernels ----------------

__global__ void zero_kernel(float* deg, float* ea_sum, int* fill) {
    int i = blockIdx.x * blockDim.x + threadIdx.x;
    if (i < 2 * N_NODES) ea_sum[i] = 0.0f;
    if (i < N_NODES) { deg[i] = 0.0f; fill[i] = 0; }
}

__global__ void deg_kernel(const int* __restrict__ ei, const float* __restrict__ edge_attr,
                           float* deg, float* ea_sum) {
    int e = blockIdx.x * blockDim.x + threadIdx.x;
    if (e >= E_EDGES) return;
    int d = ei[E_EDGES + e];
    atomicAdd(&deg[d], 1.0f);
    atomicAdd(&ea_sum[2 * d + 0], edge_attr[2 * e + 0]);
    atomicAdd(&ea_sum[2 * d + 1], edge_attr[2 * e + 1]);
}

__global__ void eamean_kernel(const float* __restrict__ deg, float* ea_mean) {
    int i = blockIdx.x * blockDim.x + threadIdx.x;
    if (i >= N_NODES) return;
    float dm = fmaxf(deg[i], 1.0f);
    ea_mean[2 * i + 0] /= dm;
    ea_mean[2 * i + 1] /= dm;
}

// single-block exclusive scan of (deg[i]+1) -> row_ptr[N+1]
__global__ __launch_bounds__(1024) void scan_kernel(const float* __restrict__ deg, int* row_ptr) {
    __shared__ int part[1024];
    int t = threadIdx.x;
    int base = t * 32;
    int loc[32];
    int s = 0;
    #pragma unroll
    for (int j = 0; j < 32; j++) {
        loc[j] = s;
        s += (int)deg[base + j] + 1;
    }
    int mysum = s;
    part[t] = s;
    __syncthreads();
    for (int off = 1; off < 1024; off <<= 1) {
        int v = 0;
        if (t >= off) v = part[t - off];
        __syncthreads();
        part[t] += v;
        __syncthreads();
    }
    int offset = part[t] - mysum;
    #pragma unroll
    for (int j = 0; j < 32; j++) row_ptr[base + j] = offset + loc[j];
    if (t == 1023) row_ptr[N_NODES] = part[1023];
}

__global__ void fill_kernel(const int* __restrict__ ei, const int* __restrict__ row_ptr,
                            int* fill, int* col) {
    int tid = blockIdx.x * blockDim.x + threadIdx.x;
    if (tid >= E_EDGES + N_NODES) return;
    int d;
    if (tid < E_EDGES) d = ei[E_EDGES + tid];
    else               d = tid - E_EDGES;
    int pos = row_ptr[d] + atomicAdd(&fill[d], 1);
    col[pos] = tid;
}

// ---------------- tiled GEMM: C = A @ B(^T) + bias (+gelu | +res) ----------------
// TA: A dtype (float | bf16). TC: C/res dtype. EPI: 0 bias, 1 bias+gelu, 2 bias+res.
template <typename TA, typename TC, int TRANS_B, int EPI>
__global__ __launch_bounds__(256) void gemm_kernel(
    const TA* __restrict__ A, const float* __restrict__ B,
    const float* __restrict__ bias, const TC* __restrict__ res,
    TC* __restrict__ C, int M, int Nc, int K)
{
    __shared__ float As[16][68];
    __shared__ float Bs[16][68];
    int tid = threadIdx.x;
    int n0 = blockIdx.x * 64;
    int m0 = blockIdx.y * 64;
    int tm = tid / 16, tn = tid % 16;
    float acc[4][4] = {};

    int ar  = tid / 4;          // A tile row 0..63
    int akq = (tid % 4) * 4;    // A tile k 0,4,8,12

    for (int k0 = 0; k0 < K; k0 += 16) {
        float4 a4 = load4(&A[(size_t)(m0 + ar) * K + k0 + akq]);
        As[akq + 0][ar] = a4.x; As[akq + 1][ar] = a4.y;
        As[akq + 2][ar] = a4.z; As[akq + 3][ar] = a4.w;
        if (TRANS_B) {
            int nl = tid / 4, kq = (tid % 4) * 4;
            float4 b4 = *(const float4*)&B[(size_t)(n0 + nl) * K + k0 + kq];
            Bs[kq + 0][nl] = b4.x; Bs[kq + 1][nl] = b4.y;
            Bs[kq + 2][nl] = b4.z; Bs[kq + 3][nl] = b4.w;
        } else {
            int kr = tid / 16, nq = (tid % 16) * 4;
            float4 b4 = *(const float4*)&B[(size_t)(k0 + kr) * Nc + n0 + nq];
            *(float4*)&Bs[kr][nq] = b4;
        }
        __syncthreads();
        #pragma unroll
        for (int k = 0; k < 16; k++) {
            float4 a = *(float4*)&As[k][tm * 4];
            float4 b = *(float4*)&Bs[k][tn * 4];
            float av[4] = {a.x, a.y, a.z, a.w};
            float bv[4] = {b.x, b.y, b.z, b.w};
            #pragma unroll
            for (int i = 0; i < 4; i++)
                #pragma unroll
                for (int j = 0; j < 4; j++)
                    acc[i][j] += av[i] * bv[j];
        }
        __syncthreads();
    }

    float4 bv4 = *(const float4*)&bias[n0 + tn * 4];
    float bb[4] = {bv4.x, bv4.y, bv4.z, bv4.w};
    #pragma unroll
    for (int i = 0; i < 4; i++) {
        int row = m0 + tm * 4 + i;
        float v[4];
        #pragma unroll
        for (int j = 0; j < 4; j++) v[j] = acc[i][j] + bb[j];
        if (EPI == 1) {
            #pragma unroll
            for (int j = 0; j < 4; j++)
                v[j] = 0.5f * v[j] * (1.0f + erff(v[j] * 0.70710678118654752f));
        } else if (EPI == 2) {
            float4 r4 = load4(&res[(size_t)row * Nc + n0 + tn * 4]);
            v[0] += r4.x; v[1] += r4.y; v[2] += r4.z; v[3] += r4.w;
        }
        store4(&C[(size_t)row * Nc + n0 + tn * 4], make_float4(v[0], v[1], v[2], v[3]));
    }
}

// ---------------- GATv2 per-node attention + fused LN1 ----------------
__global__ __launch_bounds__(256) void gat_kernel(
    const bf16* __restrict__ xl, const bf16* __restrict__ xr,
    const int* __restrict__ row_ptr, const int* __restrict__ col,
    const int* __restrict__ ei, const float* __restrict__ edge_attr,
    const float* __restrict__ ea_mean,
    const float* __restrict__ W_e, const float* __restrict__ att,
    const float* __restrict__ bias_gat,
    const float* __restrict__ g1, const float* __restrict__ be1,
    bf16* __restrict__ out)
{
    int wave = threadIdx.x >> 6;
    int lane = threadIdx.x & 63;
    int node = blockIdx.x * 4 + wave;
    int cb = lane * 4;

    float4 xr4 = load4(&xr[(size_t)node * HIDDEN + cb]);
    float4 we0 = *(const float4*)&W_e[cb];
    float4 we1 = *(const float4*)&W_e[HIDDEN + cb];
    float4 at4 = *(const float4*)&att[cb];

    int rs = row_ptr[node], re = row_ptr[node + 1];
    float lsum = 0.0f;
    float acc0 = 0.f, acc1 = 0.f, acc2 = 0.f, acc3 = 0.f;

    for (int idx = rs; idx < re; idx++) {
        int eid = col[idx];
        int s; float ea0, ea1;
        if (eid < E_EDGES) {
            s = ei[eid];
            ea0 = edge_attr[2 * eid + 0];
            ea1 = edge_attr[2 * eid + 1];
        } else {
            s = node;
            ea0 = ea_mean[2 * node + 0];
            ea1 = ea_mean[2 * node + 1];
        }
        float4 xl4 = load4(&xl[(size_t)s * HIDDEN + cb]);
        float t, p = 0.0f;
        t = xl4.x + xr4.x + ea0 * we0.x + ea1 * we1.x; t = (t > 0.f) ? t : 0.2f * t; p += t * at4.x;
        t = xl4.y + xr4.y + ea0 * we0.y + ea1 * we1.y; t = (t > 0.f) ? t : 0.2f * t; p += t * at4.y;
        t = xl4.z + xr4.z + ea0 * we0.z + ea1 * we1.z; t = (t > 0.f) ? t : 0.2f * t; p += t * at4.z;
        t = xl4.w + xr4.w + ea0 * we0.w + ea1 * we1.w; t = (t > 0.f) ? t : 0.2f * t; p += t * at4.w;
        p += __shfl_xor(p, 1);
        p += __shfl_xor(p, 2);
        p += __shfl_xor(p, 4);
        float w = expf(p);
        lsum += w;
        acc0 += w * xl4.x; acc1 += w * xl4.y; acc2 += w * xl4.z; acc3 += w * xl4.w;
    }
    float inv = 1.0f / lsum;
    float v0 = acc0 * inv + bias_gat[cb + 0];
    float v1 = acc1 * inv + bias_gat[cb + 1];
    float v2 = acc2 * inv + bias_gat[cb + 2];
    float v3 = acc3 * inv + bias_gat[cb + 3];

    float s = v0 + v1 + v2 + v3;
    #pragma unroll
    for (int m = 1; m < 64; m <<= 1) s += __shfl_xor(s, m);
    float mean = s * (1.0f / 256.0f);
    float d0 = v0 - mean, d1 = v1 - mean, d2 = v2 - mean, d3 = v3 - mean;
    float sq = d0 * d0 + d1 * d1 + d2 * d2 + d3 * d3;
    #pragma unroll
    for (int m = 1; m < 64; m <<= 1) sq += __shfl_xor(sq, m);
    float rstd = rsqrtf(sq * (1.0f / 256.0f) + 1e-5f);
    float4 o;
    o.x = d0 * rstd * g1[cb + 0] + be1[cb + 0];
    o.y = d1 * rstd * g1[cb + 1] + be1[cb + 1];
    o.z = d2 * rstd * g1[cb + 2] + be1[cb + 2];
    o.w = d3 * rstd * g1[cb + 3] + be1[cb + 3];
    store4(&out[(size_t)node * HIDDEN + cb], o);
}

// ---------------- per-(graph,head) MHA core ----------------
__global__ __launch_bounds__(256) void attn_kernel(
    const bf16* __restrict__ qkv, bf16* __restrict__ attnout)
{
    __shared__ float Ks[128][36];
    __shared__ float Vs[128][36];
    int g = blockIdx.x >> 3;
    int h = blockIdx.x & 7;
    int tid = threadIdx.x;
    int q1 = tid, q2 = tid + 256;

    float4 qa[8], qb[8], acc1[8], acc2[8];
    const bf16* qrow1 = &qkv[((size_t)(g * NPG + q1)) * 768 + h * CDIM];
    const bf16* qrow2 = &qkv[((size_t)(g * NPG + q2)) * 768 + h * CDIM];
    #pragma unroll
    for (int j = 0; j < 8; j++) {
        qa[j] = load4(qrow1 + j * 4);
        qb[j] = load4(qrow2 + j * 4);
        acc1[j] = make_float4(0.f, 0.f, 0.f, 0.f);
        acc2[j] = make_float4(0.f, 0.f, 0.f, 0.f);
    }
    float l1 = 0.f, l2 = 0.f;
    const float SCALE = 0.17677669529663687f;  // 1/sqrt(32)

    for (int t0 = 0; t0 < NPG; t0 += 128) {
        __syncthreads();
        for (int i = tid; i < 128 * 8; i += 256) {
            int k = i >> 3, j = (i & 7) * 4;
            const bf16* base = &qkv[((size_t)(g * NPG + t0 + k)) * 768 + h * CDIM + j];
            *(float4*)&Ks[k][j] = load4(base + 256);
            *(float4*)&Vs[k][j] = load4(base + 512);
        }
        __syncthreads();
        for (int k = 0; k < 128; k++) {
            float s1 = 0.f, s2 = 0.f;
            #pragma unroll
            for (int j = 0; j < 8; j++) {
                float4 kk = *(float4*)&Ks[k][j * 4];
                s1 += qa[j].x * kk.x + qa[j].y * kk.y + qa[j].z * kk.z + qa[j].w * kk.w;
                s2 += qb[j].x * kk.x + qb[j].y * kk.y + qb[j].z * kk.z + qb[j].w * kk.w;
            }
            float p1 = expf(s1 * SCALE);
            float p2 = expf(s2 * SCALE);
            l1 += p1; l2 += p2;
            #pragma unroll
            for (int j = 0; j < 8; j++) {
                float4 vv = *(float4*)&Vs[k][j * 4];
                acc1[j].x += p1 * vv.x; acc1[j].y += p1 * vv.y; acc1[j].z += p1 * vv.z; acc1[j].w += p1 * vv.w;
                acc2[j].x += p2 * vv.x; acc2[j].y += p2 * vv.y; acc2[j].z += p2 * vv.z; acc2[j].w += p2 * vv.w;
            }
        }
    }
    float inv1 = 1.0f / l1, inv2 = 1.0f / l2;
    bf16* o1 = &attnout[((size_t)(g * NPG + q1)) * HIDDEN + h * CDIM];
    bf16* o2 = &attnout[((size_t)(g * NPG + q2)) * HIDDEN + h * CDIM];
    #pragma unroll
    for (int j = 0; j < 8; j++) {
        float4 a = acc1[j], b = acc2[j];
        a.x *= inv1; a.y *= inv1; a.z *= inv1; a.w *= inv1;
        b.x *= inv2; b.y *= inv2; b.z *= inv2; b.w *= inv2;
        store4(o1 + j * 4, a);
        store4(o2 + j * 4, b);
    }
}

// ---------------- LN2(gout) + gated combine ----------------
__global__ __launch_bounds__(256) void combine_kernel(
    const bf16* __restrict__ gout, const bf16* __restrict__ localout,
    const float* __restrict__ alpha_p,
    const float* __restrict__ g2, const float* __restrict__ be2,
    bf16* __restrict__ combined)
{
    int wave = threadIdx.x >> 6;
    int lane = threadIdx.x & 63;
    int node = blockIdx.x * 4 + wave;
    int cb = lane * 4;
    float4 gv = load4(&gout[(size_t)node * HIDDEN + cb]);
    float s = gv.x + gv.y + gv.z + gv.w;
    #pragma unroll
    for (int m = 1; m < 64; m <<= 1) s += __shfl_xor(s, m);
    float mean = s * (1.0f / 256.0f);
    float d0 = gv.x - mean, d1 = gv.y - mean, d2 = gv.z - mean, d3 = gv.w - mean;
    float sq = d0 * d0 + d1 * d1 + d2 * d2 + d3 * d3;
    #pragma unroll
    for (int m = 1; m < 64; m <<= 1) sq += __shfl_xor(sq, m);
    float rstd = rsqrtf(sq * (1.0f / 256.0f) + 1e-5f);
    float n0 = d0 * rstd * g2[cb + 0] + be2[cb + 0];
    float n1 = d1 * rstd * g2[cb + 1] + be2[cb + 1];
    float n2 = d2 * rstd * g2[cb + 2] + be2[cb + 2];
    float n3 = d3 * rstd * g2[cb + 3] + be2[cb + 3];
    float a = 1.0f / (1.0f + expf(-alpha_p[0]));
    float4 lv = load4(&localout[(size_t)node * HIDDEN + cb]);
    float4 o;
    o.x = a * lv.x + (1.0f - a) * n0;
    o.y = a * lv.y + (1.0f - a) * n1;
    o.z = a * lv.z + (1.0f - a) * n2;
    o.w = a * lv.w + (1.0f - a) * n3;
    store4(&combined[(size_t)node * HIDDEN + cb], o);
}

// ---------------- final LN3 ----------------
__global__ __launch_bounds__(256) void finalln_kernel(
    const bf16* __restrict__ ffn,
    const float* __restrict__ g3, const float* __restrict__ be3,
    float* __restrict__ out)
{
    int wave = threadIdx.x >> 6;
    int lane = threadIdx.x & 63;
    int node = blockIdx.x * 4 + wave;
    int cb = lane * 4;
    float4 v = load4(&ffn[(size_t)node * HIDDEN + cb]);
    float s = v.x + v.y + v.z + v.w;
    #pragma unroll
    for (int m = 1; m < 64; m <<= 1) s += __shfl_xor(s, m);
    float mean = s * (1.0f / 256.0f);
    float d0 = v.x - mean, d1 = v.y - mean, d2 = v.z - mean, d3 = v.w - mean;
    float sq = d0 * d0 + d1 * d1 + d2 * d2 + d3 * d3;
    #pragma unroll
    for (int m = 1; m < 64; m <<= 1) sq += __shfl_xor(sq, m);
    float rstd = rsqrtf(sq * (1.0f / 256.0f) + 1e-5f);
    float4 o;
    o.x = d0 * rstd * g3[cb + 0] + be3[cb + 0];
    o.y = d1 * rstd * g3[cb + 1] + be3[cb + 1];
    o.z = d2 * rstd * g3[cb + 2] + be3[cb + 2];
    o.w = d3 * rstd * g3[cb + 3] + be3[cb + 3];
    *(float4*)&out[(size_t)node * HIDDEN + cb] = o;
}

// ---------------- launch ----------------
extern "C" void kernel_launch(void* const* d_in, const int* in_sizes, int n_in,
                              void* d_out, int out_size, void* d_ws, size_t ws_size,
                              hipStream_t stream) {
    const float* x          = (const float*)d_in[0];
    const float* edge_attr  = (const float*)d_in[1];
    const float* W_l        = (const float*)d_in[2];
    const float* b_l        = (const float*)d_in[3];
    const float* W_r        = (const float*)d_in[4];
    const float* b_r        = (const float*)d_in[5];
    const float* W_e        = (const float*)d_in[6];
    const float* att        = (const float*)d_in[7];
    const float* bias_gat   = (const float*)d_in[8];
    const float* in_proj_w  = (const float*)d_in[9];
    const float* in_proj_b  = (const float*)d_in[10];
    const float* out_proj_w = (const float*)d_in[11];
    const float* out_proj_b = (const float*)d_in[12];
    const float* alpha_p    = (const float*)d_in[13];
    const float* W1         = (const float*)d_in[14];
    const float* b1         = (const float*)d_in[15];
    const float* W2         = (const float*)d_in[16];
    const float* b2         = (const float*)d_in[17];
    const float* g1  = (const float*)d_in[18];
    const float* be1 = (const float*)d_in[19];
    const float* g2  = (const float*)d_in[20];
    const float* be2 = (const float*)d_in[21];
    const float* g3  = (const float*)d_in[22];
    const float* be3 = (const float*)d_in[23];
    const int* edge_index = (const int*)d_in[24];

    char* base = (char*)d_ws;
    const size_t MB = 1024 * 1024;
    // graph prep region [0, ~3 MiB)
    float* deg     = (float*)(base + 0);
    float* ea_mean = (float*)(base + 131072);
    int*   fill    = (int*)  (base + 393216);
    int*   row_ptr = (int*)  (base + 524288);
    int*   col     = (int*)  (base + 786432);
    // big bf16 buffers (aliased per schedule; peak 100 MiB)
    bf16* qkv      = (bf16*)(base + 4 * MB);    // [4,52)
    bf16* attnout  = (bf16*)(base + 52 * MB);   // [52,68)
    bf16* gout     = (bf16*)(base + 68 * MB);   // [68,84)
    bf16* xl       = (bf16*)(base + 4 * MB);    // [4,20)   (qkv dead)
    bf16* xr       = (bf16*)(base + 20 * MB);   // [20,36)
    bf16* localout = (bf16*)(base + 36 * MB);   // [36,52)
    bf16* combined = (bf16*)(base + 4 * MB);    // [4,20)   (xl dead)
    bf16* h1       = (bf16*)(base + 20 * MB);   // [20,84)  (xr/localout/gout dead)
    bf16* ffn      = (bf16*)(base + 84 * MB);   // [84,100)
    float* out = (float*)d_out;

    // ---- GAT graph prep ----
    zero_kernel<<<(2 * N_NODES + 255) / 256, 256, 0, stream>>>(deg, ea_mean, fill);
    deg_kernel<<<E_EDGES / 256, 256, 0, stream>>>(edge_index, edge_attr, deg, ea_mean);
    eamean_kernel<<<N_NODES / 256, 256, 0, stream>>>(deg, ea_mean);
    scan_kernel<<<1, 1024, 0, stream>>>(deg, row_ptr);
    fill_kernel<<<(E_EDGES + N_NODES) / 256, 256, 0, stream>>>(edge_index, row_ptr, fill, col);

    // ---- MHA path first (frees qkv region before GAT) ----
    gemm_kernel<float, bf16, 1, 0><<<dim3(768 / 64, N_NODES / 64), 256, 0, stream>>>(
        x, in_proj_w, in_proj_b, (const bf16*)nullptr, qkv, N_NODES, 768, HIDDEN);
    attn_kernel<<<NGRAPH * NHEAD, 256, 0, stream>>>(qkv, attnout);
    gemm_kernel<bf16, bf16, 1, 0><<<dim3(HIDDEN / 64, N_NODES / 64), 256, 0, stream>>>(
        attnout, out_proj_w, out_proj_b, (const bf16*)nullptr, gout, N_NODES, HIDDEN, HIDDEN);

    // ---- GAT path ----
    gemm_kernel<float, bf16, 0, 0><<<dim3(HIDDEN / 64, N_NODES / 64), 256, 0, stream>>>(
        x, W_l, b_l, (const bf16*)nullptr, xl, N_NODES, HIDDEN, HIDDEN);
    gemm_kernel<float, bf16, 0, 0><<<dim3(HIDDEN / 64, N_NODES / 64), 256, 0, stream>>>(
        x, W_r, b_r, (const bf16*)nullptr, xr, N_NODES, HIDDEN, HIDDEN);
    gat_kernel<<<N_NODES / 4, 256, 0, stream>>>(
        xl, xr, row_ptr, col, edge_index, edge_attr, ea_mean,
        W_e, att, bias_gat, g1, be1, localout);

    // ---- LN2 + gated combine ----
    combine_kernel<<<N_NODES / 4, 256, 0, stream>>>(
        gout, localout, alpha_p, g2, be2, combined);

    // ---- FFN ----
    gemm_kernel<bf16, bf16, 0, 1><<<dim3(1024 / 64, N_NODES / 64), 256, 0, stream>>>(
        combined, W1, b1, (const bf16*)nullptr, h1, N_NODES, 1024, HIDDEN);
    gemm_kernel<bf16, bf16, 0, 2><<<dim3(HIDDEN / 64, N_NODES / 64), 256, 0, stream>>>(
        h1, W2, b2, combined, ffn, N_NODES, HIDDEN, 1024);

    // ---- LN3 -> out ----
    finalln_kernel<<<N_NODES / 4, 256, 0, stream>>>(ffn, g3, be3, out);
}

// Round 3
// 630.686 us; speedup vs baseline: 2.5222x; 2.5222x over previous
//
#include <hip/hip_runtime.h>
#include <math.h>

#define N_NODES 32768
#define E_EDGES 524288
#define HIDDEN  256
#define NPG     512
#define NGRAPH  64
#define NHEAD   8
#define CDIM    32

typedef unsigned short bf16;
typedef __attribute__((ext_vector_type(8))) short short8;
typedef __attribute__((ext_vector_type(4))) float f4;

// ---------------- bf16 helpers (manual, RNE) ----------------
__device__ inline float bf2f(unsigned short u) {
    union { unsigned int i; float f; } v; v.i = ((unsigned int)u) << 16; return v.f;
}
__device__ inline unsigned short f2bf(float f) {
    union { float f; unsigned int i; } v; v.f = f;
    unsigned int x = v.i;
    return (unsigned short)((x + 0x7FFFu + ((x >> 16) & 1u)) >> 16);
}
__device__ inline float4 load4(const float* p) { return *(const float4*)p; }
__device__ inline float4 load4(const bf16* p) {
    ushort4 u = *(const ushort4*)p;
    return make_float4(bf2f(u.x), bf2f(u.y), bf2f(u.z), bf2f(u.w));
}
__device__ inline void store4(float* p, float4 v) { *(float4*)p = v; }
__device__ inline void store4(bf16* p, float4 v) {
    ushort4 u; u.x = f2bf(v.x); u.y = f2bf(v.y); u.z = f2bf(v.z); u.w = f2bf(v.w);
    *(ushort4*)p = u;
}

// ---------------- small utility kernels ----------------

__global__ void zero_kernel(float* deg, float* ea_sum, int* fill) {
    int i = blockIdx.x * blockDim.x + threadIdx.x;
    if (i < 2 * N_NODES) ea_sum[i] = 0.0f;
    if (i < N_NODES) { deg[i] = 0.0f; fill[i] = 0; }
}

__global__ void deg_kernel(const int* __restrict__ ei, const float* __restrict__ edge_attr,
                           float* deg, float* ea_sum) {
    int e = blockIdx.x * blockDim.x + threadIdx.x;
    if (e >= E_EDGES) return;
    int d = ei[E_EDGES + e];
    atomicAdd(&deg[d], 1.0f);
    atomicAdd(&ea_sum[2 * d + 0], edge_attr[2 * e + 0]);
    atomicAdd(&ea_sum[2 * d + 1], edge_attr[2 * e + 1]);
}

__global__ void eamean_kernel(const float* __restrict__ deg, float* ea_mean) {
    int i = blockIdx.x * blockDim.x + threadIdx.x;
    if (i >= N_NODES) return;
    float dm = fmaxf(deg[i], 1.0f);
    ea_mean[2 * i + 0] /= dm;
    ea_mean[2 * i + 1] /= dm;
}

__global__ __launch_bounds__(1024) void scan_kernel(const float* __restrict__ deg, int* row_ptr) {
    __shared__ int part[1024];
    int t = threadIdx.x;
    int base = t * 32;
    int loc[32];
    int s = 0;
    #pragma unroll
    for (int j = 0; j < 32; j++) {
        loc[j] = s;
        s += (int)deg[base + j] + 1;
    }
    int mysum = s;
    part[t] = s;
    __syncthreads();
    for (int off = 1; off < 1024; off <<= 1) {
        int v = 0;
        if (t >= off) v = part[t - off];
        __syncthreads();
        part[t] += v;
        __syncthreads();
    }
    int offset = part[t] - mysum;
    #pragma unroll
    for (int j = 0; j < 32; j++) row_ptr[base + j] = offset + loc[j];
    if (t == 1023) row_ptr[N_NODES] = part[1023];
}

__global__ void fill_kernel(const int* __restrict__ ei, const int* __restrict__ row_ptr,
                            int* fill, int* col) {
    int tid = blockIdx.x * blockDim.x + threadIdx.x;
    if (tid >= E_EDGES + N_NODES) return;
    int d;
    if (tid < E_EDGES) d = ei[E_EDGES + tid];
    else               d = tid - E_EDGES;
    int pos = row_ptr[d] + atomicAdd(&fill[d], 1);
    col[pos] = tid;
}

// ---------------- conversion kernels ----------------
// src[K][N] fp32 -> dst[n][k] bf16 (transpose)
__global__ void convw_t(const float* __restrict__ src, bf16* __restrict__ dst, int K, int N) {
    int i = blockIdx.x * 256 + threadIdx.x;
    if (i >= K * N) return;
    int k = i / N, n = i - k * N;
    dst[n * K + k] = f2bf(src[i]);
}
// straight fp32 -> bf16 (vectorized x4)
__global__ void convv(const float* __restrict__ src, bf16* __restrict__ dst, int total4) {
    int i = blockIdx.x * 256 + threadIdx.x;
    if (i >= total4) return;
    float4 v = *(const float4*)&src[i * 4];
    store4(&dst[i * 4], v);
}

// ---------------- MFMA bf16 GEMM: C[m][n] = A[m][k] * Wb[n][k]^T + bias (+gelu|+res) ----
// BM=128, BN=128, BK=64. 256 threads = 4 waves, each 64x64.
// EPI: 0 bias, 1 bias+gelu, 2 bias+residual
template <int EPI>
__global__ __launch_bounds__(256) void mfma_gemm(
    const bf16* __restrict__ A, const bf16* __restrict__ Wb,
    const float* __restrict__ bias, const bf16* __restrict__ res,
    bf16* __restrict__ C, int M, int N, int K)
{
    __shared__ bf16 lds[2 * 128 * 72];
    bf16* As = lds;
    bf16* Bs = lds + 128 * 72;
    int tid = threadIdx.x;
    int wave = tid >> 6, lane = tid & 63;
    int quad = lane >> 4, l16 = lane & 15;
    int n0 = blockIdx.x * 128, m0 = blockIdx.y * 128;
    int wm = (wave & 1) * 64, wn = (wave >> 1) * 64;

    f4 acc[4][4] = {};

    for (int k0 = 0; k0 < K; k0 += 64) {
        #pragma unroll
        for (int i = 0; i < 4; i++) {
            int idx = i * 256 + tid;
            int row = idx >> 3, kc = (idx & 7) * 8;
            *(int4*)&As[row * 72 + kc] = *(const int4*)&A[(size_t)(m0 + row) * K + k0 + kc];
            *(int4*)&Bs[row * 72 + kc] = *(const int4*)&Wb[(size_t)(n0 + row) * K + k0 + kc];
        }
        __syncthreads();
        #pragma unroll
        for (int ks = 0; ks < 2; ks++) {
            short8 af[4], bfr[4];
            #pragma unroll
            for (int mt = 0; mt < 4; mt++)
                af[mt] = *(const short8*)&As[(wm + mt * 16 + l16) * 72 + ks * 32 + quad * 8];
            #pragma unroll
            for (int nt = 0; nt < 4; nt++)
                bfr[nt] = *(const short8*)&Bs[(wn + nt * 16 + l16) * 72 + ks * 32 + quad * 8];
            #pragma unroll
            for (int mt = 0; mt < 4; mt++)
                #pragma unroll
                for (int nt = 0; nt < 4; nt++)
                    acc[mt][nt] = __builtin_amdgcn_mfma_f32_16x16x32_bf16(
                        af[mt], bfr[nt], acc[mt][nt], 0, 0, 0);
        }
        __syncthreads();
    }

    // epilogue: per-wave LDS transpose for coalesced bf16 stores
    float* epi = (float*)lds + wave * 16 * 68;
    int row = lane >> 2;          // 0..15
    int cb = (lane & 3) * 16;     // col block in wave tile
    int gn = n0 + wn + cb;
    float bb[16];
    *(float4*)&bb[0]  = *(const float4*)&bias[gn + 0];
    *(float4*)&bb[4]  = *(const float4*)&bias[gn + 4];
    *(float4*)&bb[8]  = *(const float4*)&bias[gn + 8];
    *(float4*)&bb[12] = *(const float4*)&bias[gn + 12];

    for (int mt = 0; mt < 4; mt++) {
        #pragma unroll
        for (int nt = 0; nt < 4; nt++)
            #pragma unroll
            for (int r = 0; r < 4; r++)
                epi[(quad * 4 + r) * 68 + nt * 16 + l16] = acc[mt][nt][r];
        // same-wave DS ops are in-order; read back transposed
        float vv[16];
        *(float4*)&vv[0]  = *(float4*)&epi[row * 68 + cb + 0];
        *(float4*)&vv[4]  = *(float4*)&epi[row * 68 + cb + 4];
        *(float4*)&vv[8]  = *(float4*)&epi[row * 68 + cb + 8];
        *(float4*)&vv[12] = *(float4*)&epi[row * 68 + cb + 12];
        int gm = m0 + wm + mt * 16 + row;
        #pragma unroll
        for (int j = 0; j < 16; j++) vv[j] += bb[j];
        if (EPI == 1) {
            #pragma unroll
            for (int j = 0; j < 16; j++)
                vv[j] = 0.5f * vv[j] * (1.0f + erff(vv[j] * 0.70710678118654752f));
        } else if (EPI == 2) {
            ushort rr[16];
            const bf16* rp = &res[(size_t)gm * N + gn];
            *(int4*)&rr[0] = *(const int4*)&rp[0];
            *(int4*)&rr[8] = *(const int4*)&rp[8];
            #pragma unroll
            for (int j = 0; j < 16; j++) vv[j] += bf2f(rr[j]);
        }
        ushort o16[16];
        #pragma unroll
        for (int j = 0; j < 16; j++) o16[j] = f2bf(vv[j]);
        bf16* cp = &C[(size_t)gm * N + gn];
        *(int4*)&cp[0] = *(int4*)&o16[0];
        *(int4*)&cp[8] = *(int4*)&o16[8];
    }
}

// ---------------- MFMA flash attention: one block = (g, h, q-half of 256) ----------
__global__ __launch_bounds__(256) void attn_mfma(
    const bf16* __restrict__ qkv, bf16* __restrict__ attnout)
{
    __shared__ bf16 Ks[128 * 40];      // [key][k], stride 40
    __shared__ bf16 Vt[32 * 136];      // [d][key], stride 136
    __shared__ bf16 Pb[4 * 64 * 40];   // per-wave [q][key], stride 40

    int b = blockIdx.x;                // 1024 = g*16 + h*2 + half
    int g = b >> 4, h = (b >> 1) & 7, hlf = b & 1;
    int tid = threadIdx.x;
    int wave = tid >> 6, lane = tid & 63;
    int quad = lane >> 4, l16 = lane & 15;
    int qbase = hlf * 256 + wave * 64;
    bf16* Pw = &Pb[wave * 64 * 40];
    const float SCALE = 0.17677669529663687f;

    // Q fragments: resident for whole kernel (k=32 = one mfma K-step)
    short8 qf[4];
    #pragma unroll
    for (int mt = 0; mt < 4; mt++) {
        size_t node = (size_t)(g * NPG + qbase + mt * 16 + l16);
        qf[mt] = *(const short8*)&qkv[node * 768 + h * CDIM + quad * 8];
    }

    f4 oacc[4][2] = {};
    float lacc[4][4] = {};

    for (int c = 0; c < 4; c++) {
        int kk0 = c * 128;
        __syncthreads();
        // stage K chunk [128][32]
        #pragma unroll
        for (int i = 0; i < 2; i++) {
            int idx = i * 256 + tid;
            int key = idx >> 2, kc = (idx & 3) * 8;
            *(int4*)&Ks[key * 40 + kc] =
                *(const int4*)&qkv[(size_t)(g * NPG + kk0 + key) * 768 + 256 + h * CDIM + kc];
        }
        // stage V chunk transposed -> Vt[d][key]
        {
            int key = tid >> 1, dblk = (tid & 1) * 16;
            ushort tmp[16];
            const bf16* vp = &qkv[(size_t)(g * NPG + kk0 + key) * 768 + 512 + h * CDIM + dblk];
            *(int4*)&tmp[0] = *(const int4*)&vp[0];
            *(int4*)&tmp[8] = *(const int4*)&vp[8];
            #pragma unroll
            for (int j = 0; j < 16; j++) Vt[(dblk + j) * 136 + key] = tmp[j];
        }
        __syncthreads();

        for (int sub = 0; sub < 4; sub++) {
            int ks0 = sub * 32;
            short8 kf[2];
            #pragma unroll
            for (int nt = 0; nt < 2; nt++)
                kf[nt] = *(const short8*)&Ks[(ks0 + nt * 16 + l16) * 40 + quad * 8];
            // S = QK^T, exp, write P (C-layout -> LDS [q][key])
            #pragma unroll
            for (int mt = 0; mt < 4; mt++) {
                #pragma unroll
                for (int nt = 0; nt < 2; nt++) {
                    f4 z = {0.f, 0.f, 0.f, 0.f};
                    f4 s = __builtin_amdgcn_mfma_f32_16x16x32_bf16(qf[mt], kf[nt], z, 0, 0, 0);
                    #pragma unroll
                    for (int r = 0; r < 4; r++) {
                        float p = __expf(s[r] * SCALE);
                        lacc[mt][r] += p;
                        Pw[(mt * 16 + quad * 4 + r) * 40 + nt * 16 + l16] = f2bf(p);
                    }
                }
            }
            // O += P V  (same-wave DS in-order guarantees P visibility)
            short8 vf[2];
            #pragma unroll
            for (int dt = 0; dt < 2; dt++)
                vf[dt] = *(const short8*)&Vt[(dt * 16 + l16) * 136 + ks0 + quad * 8];
            #pragma unroll
            for (int mt = 0; mt < 4; mt++) {
                short8 pf = *(const short8*)&Pw[(mt * 16 + l16) * 40 + quad * 8];
                #pragma unroll
                for (int dt = 0; dt < 2; dt++)
                    oacc[mt][dt] = __builtin_amdgcn_mfma_f32_16x16x32_bf16(
                        pf, vf[dt], oacc[mt][dt], 0, 0, 0);
            }
        }
    }

    // reduce row sums across the 16 cols (lanes sharing a quad)
    #pragma unroll
    for (int mt = 0; mt < 4; mt++)
        #pragma unroll
        for (int r = 0; r < 4; r++) {
            float l = lacc[mt][r];
            l += __shfl_xor(l, 1);
            l += __shfl_xor(l, 2);
            l += __shfl_xor(l, 4);
            l += __shfl_xor(l, 8);
            lacc[mt][r] = l;
        }

    #pragma unroll
    for (int mt = 0; mt < 4; mt++) {
        #pragma unroll
        for (int dt = 0; dt < 2; dt++) {
            #pragma unroll
            for (int r = 0; r < 4; r++) {
                float v = oacc[mt][dt][r] / lacc[mt][r];
                size_t node = (size_t)(g * NPG + qbase + mt * 16 + quad * 4 + r);
                attnout[node * HIDDEN + h * CDIM + dt * 16 + l16] = f2bf(v);
            }
        }
    }
}

// ---------------- GATv2 per-node attention + fused LN1 ----------------
__global__ __launch_bounds__(256) void gat_kernel(
    const bf16* __restrict__ xl, const bf16* __restrict__ xr,
    const int* __restrict__ row_ptr, const int* __restrict__ col,
    const int* __restrict__ ei, const float* __restrict__ edge_attr,
    const float* __restrict__ ea_mean,
    const float* __restrict__ W_e, const float* __restrict__ att,
    const float* __restrict__ bias_gat,
    const float* __restrict__ g1, const float* __restrict__ be1,
    bf16* __restrict__ out)
{
    int wave = threadIdx.x >> 6;
    int lane = threadIdx.x & 63;
    int node = blockIdx.x * 4 + wave;
    int cb = lane * 4;

    float4 xr4 = load4(&xr[(size_t)node * HIDDEN + cb]);
    float4 we0 = *(const float4*)&W_e[cb];
    float4 we1 = *(const float4*)&W_e[HIDDEN + cb];
    float4 at4 = *(const float4*)&att[cb];

    int rs = row_ptr[node], re = row_ptr[node + 1];
    float lsum = 0.0f;
    float acc0 = 0.f, acc1 = 0.f, acc2 = 0.f, acc3 = 0.f;

    for (int idx = rs; idx < re; idx++) {
        int eid = col[idx];
        int s; float ea0, ea1;
        if (eid < E_EDGES) {
            s = ei[eid];
            ea0 = edge_attr[2 * eid + 0];
            ea1 = edge_attr[2 * eid + 1];
        } else {
            s = node;
            ea0 = ea_mean[2 * node + 0];
            ea1 = ea_mean[2 * node + 1];
        }
        float4 xl4 = load4(&xl[(size_t)s * HIDDEN + cb]);
        float t, p = 0.0f;
        t = xl4.x + xr4.x + ea0 * we0.x + ea1 * we1.x; t = (t > 0.f) ? t : 0.2f * t; p += t * at4.x;
        t = xl4.y + xr4.y + ea0 * we0.y + ea1 * we1.y; t = (t > 0.f) ? t : 0.2f * t; p += t * at4.y;
        t = xl4.z + xr4.z + ea0 * we0.z + ea1 * we1.z; t = (t > 0.f) ? t : 0.2f * t; p += t * at4.z;
        t = xl4.w + xr4.w + ea0 * we0.w + ea1 * we1.w; t = (t > 0.f) ? t : 0.2f * t; p += t * at4.w;
        p += __shfl_xor(p, 1);
        p += __shfl_xor(p, 2);
        p += __shfl_xor(p, 4);
        float w = __expf(p);
        lsum += w;
        acc0 += w * xl4.x; acc1 += w * xl4.y; acc2 += w * xl4.z; acc3 += w * xl4.w;
    }
    float inv = 1.0f / lsum;
    float v0 = acc0 * inv + bias_gat[cb + 0];
    float v1 = acc1 * inv + bias_gat[cb + 1];
    float v2 = acc2 * inv + bias_gat[cb + 2];
    float v3 = acc3 * inv + bias_gat[cb + 3];

    float s = v0 + v1 + v2 + v3;
    #pragma unroll
    for (int m = 1; m < 64; m <<= 1) s += __shfl_xor(s, m);
    float mean = s * (1.0f / 256.0f);
    float d0 = v0 - mean, d1 = v1 - mean, d2 = v2 - mean, d3 = v3 - mean;
    float sq = d0 * d0 + d1 * d1 + d2 * d2 + d3 * d3;
    #pragma unroll
    for (int m = 1; m < 64; m <<= 1) sq += __shfl_xor(sq, m);
    float rstd = rsqrtf(sq * (1.0f / 256.0f) + 1e-5f);
    float4 o;
    o.x = d0 * rstd * g1[cb + 0] + be1[cb + 0];
    o.y = d1 * rstd * g1[cb + 1] + be1[cb + 1];
    o.z = d2 * rstd * g1[cb + 2] + be1[cb + 2];
    o.w = d3 * rstd * g1[cb + 3] + be1[cb + 3];
    store4(&out[(size_t)node * HIDDEN + cb], o);
}

// ---------------- LN2(gout) + gated combine ----------------
__global__ __launch_bounds__(256) void combine_kernel(
    const bf16* __restrict__ gout, const bf16* __restrict__ localout,
    const float* __restrict__ alpha_p,
    const float* __restrict__ g2, const float* __restrict__ be2,
    bf16* __restrict__ combined)
{
    int wave = threadIdx.x >> 6;
    int lane = threadIdx.x & 63;
    int node = blockIdx.x * 4 + wave;
    int cb = lane * 4;
    float4 gv = load4(&gout[(size_t)node * HIDDEN + cb]);
    float s = gv.x + gv.y + gv.z + gv.w;
    #pragma unroll
    for (int m = 1; m < 64; m <<= 1) s += __shfl_xor(s, m);
    float mean = s * (1.0f / 256.0f);
    float d0 = gv.x - mean, d1 = gv.y - mean, d2 = gv.z - mean, d3 = gv.w - mean;
    float sq = d0 * d0 + d1 * d1 + d2 * d2 + d3 * d3;
    #pragma unroll
    for (int m = 1; m < 64; m <<= 1) sq += __shfl_xor(sq, m);
    float rstd = rsqrtf(sq * (1.0f / 256.0f) + 1e-5f);
    float n0 = d0 * rstd * g2[cb + 0] + be2[cb + 0];
    float n1 = d1 * rstd * g2[cb + 1] + be2[cb + 1];
    float n2 = d2 * rstd * g2[cb + 2] + be2[cb + 2];
    float n3 = d3 * rstd * g2[cb + 3] + be2[cb + 3];
    float a = 1.0f / (1.0f + __expf(-alpha_p[0]));
    float4 lv = load4(&localout[(size_t)node * HIDDEN + cb]);
    float4 o;
    o.x = a * lv.x + (1.0f - a) * n0;
    o.y = a * lv.y + (1.0f - a) * n1;
    o.z = a * lv.z + (1.0f - a) * n2;
    o.w = a * lv.w + (1.0f - a) * n3;
    store4(&combined[(size_t)node * HIDDEN + cb], o);
}

// ---------------- final LN3 ----------------
__global__ __launch_bounds__(256) void finalln_kernel(
    const bf16* __restrict__ ffn,
    const float* __restrict__ g3, const float* __restrict__ be3,
    float* __restrict__ out)
{
    int wave = threadIdx.x >> 6;
    int lane = threadIdx.x & 63;
    int node = blockIdx.x * 4 + wave;
    int cb = lane * 4;
    float4 v = load4(&ffn[(size_t)node * HIDDEN + cb]);
    float s = v.x + v.y + v.z + v.w;
    #pragma unroll
    for (int m = 1; m < 64; m <<= 1) s += __shfl_xor(s, m);
    float mean = s * (1.0f / 256.0f);
    float d0 = v.x - mean, d1 = v.y - mean, d2 = v.z - mean, d3 = v.w - mean;
    float sq = d0 * d0 + d1 * d1 + d2 * d2 + d3 * d3;
    #pragma unroll
    for (int m = 1; m < 64; m <<= 1) sq += __shfl_xor(sq, m);
    float rstd = rsqrtf(sq * (1.0f / 256.0f) + 1e-5f);
    float4 o;
    o.x = d0 * rstd * g3[cb + 0] + be3[cb + 0];
    o.y = d1 * rstd * g3[cb + 1] + be3[cb + 1];
    o.z = d2 * rstd * g3[cb + 2] + be3[cb + 2];
    o.w = d3 * rstd * g3[cb + 3] + be3[cb + 3];
    *(float4*)&out[(size_t)node * HIDDEN + cb] = o;
}

// ---------------- launch ----------------
extern "C" void kernel_launch(void* const* d_in, const int* in_sizes, int n_in,
                              void* d_out, int out_size, void* d_ws, size_t ws_size,
                              hipStream_t stream) {
    const float* x          = (const float*)d_in[0];
    const float* edge_attr  = (const float*)d_in[1];
    const float* W_l        = (const float*)d_in[2];
    const float* b_l        = (const float*)d_in[3];
    const float* W_r        = (const float*)d_in[4];
    const float* b_r        = (const float*)d_in[5];
    const float* W_e        = (const float*)d_in[6];
    const float* att        = (const float*)d_in[7];
    const float* bias_gat   = (const float*)d_in[8];
    const float* in_proj_w  = (const float*)d_in[9];
    const float* in_proj_b  = (const float*)d_in[10];
    const float* out_proj_w = (const float*)d_in[11];
    const float* out_proj_b = (const float*)d_in[12];
    const float* alpha_p    = (const float*)d_in[13];
    const float* W1         = (const float*)d_in[14];
    const float* b1         = (const float*)d_in[15];
    const float* W2         = (const float*)d_in[16];
    const float* b2         = (const float*)d_in[17];
    const float* g1  = (const float*)d_in[18];
    const float* be1 = (const float*)d_in[19];
    const float* g2  = (const float*)d_in[20];
    const float* be2 = (const float*)d_in[21];
    const float* g3  = (const float*)d_in[22];
    const float* be3 = (const float*)d_in[23];
    const int* edge_index = (const int*)d_in[24];

    char* base = (char*)d_ws;
    const size_t MB = 1024 * 1024;
    // graph prep [0, 3 MiB)
    float* deg     = (float*)(base + 0);
    float* ea_mean = (float*)(base + 131072);
    int*   fill    = (int*)  (base + 393216);
    int*   row_ptr = (int*)  (base + 524288);
    int*   col     = (int*)  (base + 786432);
    // bf16 weights [3 MiB, 6 MiB)
    bf16* wlb  = (bf16*)(base + 3 * MB);
    bf16* wrb  = (bf16*)(base + 3 * MB + 512 * 1024);
    bf16* wipb = (bf16*)(base + 4 * MB);
    bf16* wopb = (bf16*)(base + 4 * MB + 512 * 1024);
    bf16* w1b  = (bf16*)(base + 5 * MB);
    bf16* w2b  = (bf16*)(base + 5 * MB + 512 * 1024);
    // big bf16 buffers (aliased; peak 88 MiB)
    bf16* xb       = (bf16*)(base + 8 * MB);    // [8,24)
    bf16* qkv      = (bf16*)(base + 24 * MB);   // [24,72)
    bf16* attnout  = (bf16*)(base + 72 * MB);   // [72,88)
    bf16* gout     = (bf16*)(base + 24 * MB);   // [24,40)  (qkv dead)
    bf16* xl       = (bf16*)(base + 40 * MB);   // [40,56)
    bf16* xr       = (bf16*)(base + 56 * MB);   // [56,72)
    bf16* localout = (bf16*)(base + 72 * MB);   // [72,88)  (attnout dead)
    bf16* combined = (bf16*)(base + 8 * MB);    // [8,24)   (xb dead)
    bf16* h1h      = (bf16*)(base + 24 * MB);   // [24,56)  half-sized (gout/xl dead)
    bf16* ffn      = (bf16*)(base + 56 * MB);   // [56,72)  (xr dead)
    float* out = (float*)d_out;

    // ---- GAT graph prep ----
    zero_kernel<<<(2 * N_NODES + 255) / 256, 256, 0, stream>>>(deg, ea_mean, fill);
    deg_kernel<<<E_EDGES / 256, 256, 0, stream>>>(edge_index, edge_attr, deg, ea_mean);
    eamean_kernel<<<N_NODES / 256, 256, 0, stream>>>(deg, ea_mean);
    scan_kernel<<<1, 1024, 0, stream>>>(deg, row_ptr);
    fill_kernel<<<(E_EDGES + N_NODES) / 256, 256, 0, stream>>>(edge_index, row_ptr, fill, col);

    // ---- weight + x conversion ----
    convw_t<<<256, 256, 0, stream>>>(W_l, wlb, 256, 256);
    convw_t<<<256, 256, 0, stream>>>(W_r, wrb, 256, 256);
    convw_t<<<1024, 256, 0, stream>>>(W1, w1b, 256, 1024);
    convw_t<<<1024, 256, 0, stream>>>(W2, w2b, 1024, 256);
    convv<<<192, 256, 0, stream>>>(in_proj_w, wipb, 49152);    // 196608/4
    convv<<<64, 256, 0, stream>>>(out_proj_w, wopb, 16384);    // 65536/4
    convv<<<8192, 256, 0, stream>>>(x, xb, 2097152);           // 8388608/4

    // ---- MHA path first ----
    mfma_gemm<0><<<dim3(768 / 128, N_NODES / 128), 256, 0, stream>>>(
        xb, wipb, in_proj_b, (const bf16*)nullptr, qkv, N_NODES, 768, 256);
    attn_mfma<<<NGRAPH * NHEAD * 2, 256, 0, stream>>>(qkv, attnout);
    mfma_gemm<0><<<dim3(256 / 128, N_NODES / 128), 256, 0, stream>>>(
        attnout, wopb, out_proj_b, (const bf16*)nullptr, gout, N_NODES, 256, 256);

    // ---- GAT path ----
    mfma_gemm<0><<<dim3(256 / 128, N_NODES / 128), 256, 0, stream>>>(
        xb, wlb, b_l, (const bf16*)nullptr, xl, N_NODES, 256, 256);
    mfma_gemm<0><<<dim3(256 / 128, N_NODES / 128), 256, 0, stream>>>(
        xb, wrb, b_r, (const bf16*)nullptr, xr, N_NODES, 256, 256);
    gat_kernel<<<N_NODES / 4, 256, 0, stream>>>(
        xl, xr, row_ptr, col, edge_index, edge_attr, ea_mean,
        W_e, att, bias_gat, g1, be1, localout);

    // ---- LN2 + gated combine ----
    combine_kernel<<<N_NODES / 4, 256, 0, stream>>>(
        gout, localout, alpha_p, g2, be2, combined);

    // ---- FFN in two M-halves (workspace peak control) ----
    for (int hh = 0; hh < 2; hh++) {
        const bf16* ch = combined + (size_t)hh * 16384 * 256;
        bf16* fh = ffn + (size_t)hh * 16384 * 256;
        mfma_gemm<1><<<dim3(1024 / 128, 16384 / 128), 256, 0, stream>>>(
            ch, w1b, b1, (const bf16*)nullptr, h1h, 16384, 1024, 256);
        mfma_gemm<2><<<dim3(256 / 128, 16384 / 128), 256, 0, stream>>>(
            h1h, w2b, b2, ch, fh, 16384, 256, 1024);
    }

    // ---- LN3 -> out ----
    finalln_kernel<<<N_NODES / 4, 256, 0, stream>>>(ffn, g3, be3, out);
}

// Round 4
// 609.640 us; speedup vs baseline: 2.6093x; 1.0345x over previous
//
#include <hip/hip_runtime.h>
#include <math.h>

#define N_NODES 32768
#define E_EDGES 524288
#define HIDDEN  256
#define NPG     512
#define NGRAPH  64
#define NHEAD   8
#define CDIM    32

typedef unsigned short bf16;
typedef __attribute__((ext_vector_type(8))) short short8;
typedef __attribute__((ext_vector_type(4))) float f4;

#define AS1 __attribute__((address_space(1)))
#define AS3 __attribute__((address_space(3)))

// async global->LDS 16B per lane; LDS dest must be wave-uniform base + lane*16
__device__ __forceinline__ void cp16(const bf16* g, bf16* l) {
    __builtin_amdgcn_global_load_lds((AS1 const unsigned int*)(const void*)g,
                                     (AS3 unsigned int*)(void*)l, 16, 0, 0);
}

// ---------------- bf16 helpers (manual, RNE) ----------------
__device__ inline float bf2f(unsigned short u) {
    union { unsigned int i; float f; } v; v.i = ((unsigned int)u) << 16; return v.f;
}
__device__ inline unsigned short f2bf(float f) {
    union { float f; unsigned int i; } v; v.f = f;
    unsigned int x = v.i;
    return (unsigned short)((x + 0x7FFFu + ((x >> 16) & 1u)) >> 16);
}
__device__ inline float4 load4(const float* p) { return *(const float4*)p; }
__device__ inline float4 load4(const bf16* p) {
    ushort4 u = *(const ushort4*)p;
    return make_float4(bf2f(u.x), bf2f(u.y), bf2f(u.z), bf2f(u.w));
}
__device__ inline void store4(float* p, float4 v) { *(float4*)p = v; }
__device__ inline void store4(bf16* p, float4 v) {
    ushort4 u; u.x = f2bf(v.x); u.y = f2bf(v.y); u.z = f2bf(v.z); u.w = f2bf(v.w);
    *(ushort4*)p = u;
}

// ---------------- small utility kernels ----------------

__global__ void zero_kernel(float* deg, float* ea_sum, int* fill) {
    int i = blockIdx.x * blockDim.x + threadIdx.x;
    if (i < 2 * N_NODES) ea_sum[i] = 0.0f;
    if (i < N_NODES) { deg[i] = 0.0f; fill[i] = 0; }
}

__global__ void deg_kernel(const int* __restrict__ ei, const float* __restrict__ edge_attr,
                           float* deg, float* ea_sum) {
    int e = blockIdx.x * blockDim.x + threadIdx.x;
    if (e >= E_EDGES) return;
    int d = ei[E_EDGES + e];
    atomicAdd(&deg[d], 1.0f);
    atomicAdd(&ea_sum[2 * d + 0], edge_attr[2 * e + 0]);
    atomicAdd(&ea_sum[2 * d + 1], edge_attr[2 * e + 1]);
}

__global__ void eamean_kernel(const float* __restrict__ deg, float* ea_mean) {
    int i = blockIdx.x * blockDim.x + threadIdx.x;
    if (i >= N_NODES) return;
    float dm = fmaxf(deg[i], 1.0f);
    ea_mean[2 * i + 0] /= dm;
    ea_mean[2 * i + 1] /= dm;
}

__global__ __launch_bounds__(1024) void scan_kernel(const float* __restrict__ deg, int* row_ptr) {
    __shared__ int part[1024];
    int t = threadIdx.x;
    int base = t * 32;
    int loc[32];
    int s = 0;
    #pragma unroll
    for (int j = 0; j < 32; j++) {
        loc[j] = s;
        s += (int)deg[base + j] + 1;
    }
    int mysum = s;
    part[t] = s;
    __syncthreads();
    for (int off = 1; off < 1024; off <<= 1) {
        int v = 0;
        if (t >= off) v = part[t - off];
        __syncthreads();
        part[t] += v;
        __syncthreads();
    }
    int offset = part[t] - mysum;
    #pragma unroll
    for (int j = 0; j < 32; j++) row_ptr[base + j] = offset + loc[j];
    if (t == 1023) row_ptr[N_NODES] = part[1023];
}

__global__ void fill_kernel(const int* __restrict__ ei, const int* __restrict__ row_ptr,
                            int* fill, int* col) {
    int tid = blockIdx.x * blockDim.x + threadIdx.x;
    if (tid >= E_EDGES + N_NODES) return;
    int d;
    if (tid < E_EDGES) d = ei[E_EDGES + tid];
    else               d = tid - E_EDGES;
    int pos = row_ptr[d] + atomicAdd(&fill[d], 1);
    col[pos] = tid;
}

// ---------------- all conversions in one launch ----------------
__global__ void convall(const float* __restrict__ x,
                        const float* __restrict__ W_l, const float* __restrict__ W_r,
                        const float* __restrict__ W1, const float* __restrict__ W2,
                        const float* __restrict__ in_proj_w, const float* __restrict__ out_proj_w,
                        const float* __restrict__ b_l, const float* __restrict__ b_r,
                        bf16* xb, bf16* wlrb, bf16* w1b, bf16* w2b,
                        bf16* wipb, bf16* wopb, float* blr)
{
    int b = blockIdx.x, t = threadIdx.x;
    if (b < 8192) {                      // x copy (float4)
        int i = b * 256 + t;
        store4(&xb[i * 4], *(const float4*)&x[i * 4]);
    } else if (b < 8448) {               // W_l [256][256] -> wlrb rows 0..255 [n][k]
        int i = (b - 8192) * 256 + t; int k = i >> 8, n = i & 255;
        wlrb[n * 256 + k] = f2bf(W_l[i]);
    } else if (b < 8704) {               // W_r -> wlrb rows 256..511
        int i = (b - 8448) * 256 + t; int k = i >> 8, n = i & 255;
        wlrb[(256 + n) * 256 + k] = f2bf(W_r[i]);
    } else if (b < 9728) {               // W1 [256][1024] -> w1b[n*256+k]
        int i = (b - 8704) * 256 + t; int k = i >> 10, n = i & 1023;
        w1b[n * 256 + k] = f2bf(W1[i]);
    } else if (b < 10752) {              // W2 [1024][256] -> w2b[n*1024+k]
        int i = (b - 9728) * 256 + t; int k = i >> 8, n = i & 255;
        w2b[n * 1024 + k] = f2bf(W2[i]);
    } else if (b < 10944) {              // in_proj_w [768][256] straight copy
        int i = (b - 10752) * 256 + t;
        store4(&wipb[i * 4], *(const float4*)&in_proj_w[i * 4]);
    } else if (b < 11008) {              // out_proj_w [256][256] straight copy
        int i = (b - 10944) * 256 + t;
        store4(&wopb[i * 4], *(const float4*)&out_proj_w[i * 4]);
    } else {                             // concat biases
        blr[t] = b_l[t]; blr[256 + t] = b_r[t];
    }
}

// ---------------- MFMA bf16 GEMM (m97-style staging) ----------------
// C[m][n] = A[m][k] * Wb[n][k]^T + bias (+gelu|+res). BM=BN=128, BK=64.
// EPI: 0 bias, 1 bias+gelu, 2 bias+residual
template <int EPI>
__global__ __launch_bounds__(256) void mfma_gemm(
    const bf16* __restrict__ A, const bf16* __restrict__ Wb,
    const float* __restrict__ bias, const bf16* __restrict__ res,
    bf16* __restrict__ C, int M, int N, int K)
{
    __shared__ bf16 lds[2 * 128 * 64];   // 32 KiB, unpadded (required by global_load_lds)
    bf16* As = lds;
    bf16* Bs = lds + 128 * 64;
    int tid = threadIdx.x;
    int wave = tid >> 6, lane = tid & 63;
    int quad = lane >> 4, l16 = lane & 15;
    int n0 = blockIdx.x * 128, m0 = blockIdx.y * 128;
    int wm = (wave & 1) * 64, wn = (wave >> 1) * 64;

    f4 acc[4][4] = {};

    int srow = tid >> 3;            // 0..31 base row
    int scol = (tid & 7) * 8;       // k-offset in bf16 elems (16B chunks)

    for (int k0 = 0; k0 < K; k0 += 64) {
        #pragma unroll
        for (int i = 0; i < 4; i++) {
            int row = i * 32 + srow;
            cp16(&A[(size_t)(m0 + row) * K + k0 + scol], &As[row * 64 + scol]);
            cp16(&Wb[(size_t)(n0 + row) * K + k0 + scol], &Bs[row * 64 + scol]);
        }
        __syncthreads();
        #pragma unroll
        for (int ks = 0; ks < 2; ks++) {
            short8 af[4], bfr[4];
            #pragma unroll
            for (int mt = 0; mt < 4; mt++)
                af[mt] = *(const short8*)&As[(wm + mt * 16 + l16) * 64 + ks * 32 + quad * 8];
            #pragma unroll
            for (int nt = 0; nt < 4; nt++)
                bfr[nt] = *(const short8*)&Bs[(wn + nt * 16 + l16) * 64 + ks * 32 + quad * 8];
            #pragma unroll
            for (int mt = 0; mt < 4; mt++)
                #pragma unroll
                for (int nt = 0; nt < 4; nt++)
                    acc[mt][nt] = __builtin_amdgcn_mfma_f32_16x16x32_bf16(
                        af[mt], bfr[nt], acc[mt][nt], 0, 0, 0);
        }
        __syncthreads();
    }

    // epilogue: per-wave LDS transpose for coalesced bf16 stores
    float* epi = (float*)lds + wave * 16 * 68;
    int row = lane >> 2;
    int cb = (lane & 3) * 16;
    int gn = n0 + wn + cb;
    float bb[16];
    *(float4*)&bb[0]  = *(const float4*)&bias[gn + 0];
    *(float4*)&bb[4]  = *(const float4*)&bias[gn + 4];
    *(float4*)&bb[8]  = *(const float4*)&bias[gn + 8];
    *(float4*)&bb[12] = *(const float4*)&bias[gn + 12];

    for (int mt = 0; mt < 4; mt++) {
        #pragma unroll
        for (int nt = 0; nt < 4; nt++)
            #pragma unroll
            for (int r = 0; r < 4; r++)
                epi[(quad * 4 + r) * 68 + nt * 16 + l16] = acc[mt][nt][r];
        float vv[16];
        *(float4*)&vv[0]  = *(float4*)&epi[row * 68 + cb + 0];
        *(float4*)&vv[4]  = *(float4*)&epi[row * 68 + cb + 4];
        *(float4*)&vv[8]  = *(float4*)&epi[row * 68 + cb + 8];
        *(float4*)&vv[12] = *(float4*)&epi[row * 68 + cb + 12];
        int gm = m0 + wm + mt * 16 + row;
        #pragma unroll
        for (int j = 0; j < 16; j++) vv[j] += bb[j];
        if (EPI == 1) {
            #pragma unroll
            for (int j = 0; j < 16; j++)
                vv[j] = 0.5f * vv[j] * (1.0f + erff(vv[j] * 0.70710678118654752f));
        } else if (EPI == 2) {
            ushort rr[16];
            const bf16* rp = &res[(size_t)gm * N + gn];
            *(int4*)&rr[0] = *(const int4*)&rp[0];
            *(int4*)&rr[8] = *(const int4*)&rp[8];
            #pragma unroll
            for (int j = 0; j < 16; j++) vv[j] += bf2f(rr[j]);
        }
        ushort o16[16];
        #pragma unroll
        for (int j = 0; j < 16; j++) o16[j] = f2bf(vv[j]);
        bf16* cp = &C[(size_t)gm * N + gn];
        *(int4*)&cp[0] = *(int4*)&o16[0];
        *(int4*)&cp[8] = *(int4*)&o16[8];
    }
}

// ---------------- MFMA flash attention (unchanged from R3) ----------
__global__ __launch_bounds__(256) void attn_mfma(
    const bf16* __restrict__ qkv, bf16* __restrict__ attnout)
{
    __shared__ bf16 Ks[128 * 40];
    __shared__ bf16 Vt[32 * 136];
    __shared__ bf16 Pb[4 * 64 * 40];

    int b = blockIdx.x;
    int g = b >> 4, h = (b >> 1) & 7, hlf = b & 1;
    int tid = threadIdx.x;
    int wave = tid >> 6, lane = tid & 63;
    int quad = lane >> 4, l16 = lane & 15;
    int qbase = hlf * 256 + wave * 64;
    bf16* Pw = &Pb[wave * 64 * 40];
    const float SCALE = 0.17677669529663687f;

    short8 qf[4];
    #pragma unroll
    for (int mt = 0; mt < 4; mt++) {
        size_t node = (size_t)(g * NPG + qbase + mt * 16 + l16);
        qf[mt] = *(const short8*)&qkv[node * 768 + h * CDIM + quad * 8];
    }

    f4 oacc[4][2] = {};
    float lacc[4][4] = {};

    for (int c = 0; c < 4; c++) {
        int kk0 = c * 128;
        __syncthreads();
        #pragma unroll
        for (int i = 0; i < 2; i++) {
            int idx = i * 256 + tid;
            int key = idx >> 2, kc = (idx & 3) * 8;
            *(int4*)&Ks[key * 40 + kc] =
                *(const int4*)&qkv[(size_t)(g * NPG + kk0 + key) * 768 + 256 + h * CDIM + kc];
        }
        {
            int key = tid >> 1, dblk = (tid & 1) * 16;
            ushort tmp[16];
            const bf16* vp = &qkv[(size_t)(g * NPG + kk0 + key) * 768 + 512 + h * CDIM + dblk];
            *(int4*)&tmp[0] = *(const int4*)&vp[0];
            *(int4*)&tmp[8] = *(const int4*)&vp[8];
            #pragma unroll
            for (int j = 0; j < 16; j++) Vt[(dblk + j) * 136 + key] = tmp[j];
        }
        __syncthreads();

        for (int sub = 0; sub < 4; sub++) {
            int ks0 = sub * 32;
            short8 kf[2];
            #pragma unroll
            for (int nt = 0; nt < 2; nt++)
                kf[nt] = *(const short8*)&Ks[(ks0 + nt * 16 + l16) * 40 + quad * 8];
            #pragma unroll
            for (int mt = 0; mt < 4; mt++) {
                #pragma unroll
                for (int nt = 0; nt < 2; nt++) {
                    f4 z = {0.f, 0.f, 0.f, 0.f};
                    f4 s = __builtin_amdgcn_mfma_f32_16x16x32_bf16(qf[mt], kf[nt], z, 0, 0, 0);
                    #pragma unroll
                    for (int r = 0; r < 4; r++) {
                        float p = __expf(s[r] * SCALE);
                        lacc[mt][r] += p;
                        Pw[(mt * 16 + quad * 4 + r) * 40 + nt * 16 + l16] = f2bf(p);
                    }
                }
            }
            short8 vf[2];
            #pragma unroll
            for (int dt = 0; dt < 2; dt++)
                vf[dt] = *(const short8*)&Vt[(dt * 16 + l16) * 136 + ks0 + quad * 8];
            #pragma unroll
            for (int mt = 0; mt < 4; mt++) {
                short8 pf = *(const short8*)&Pw[(mt * 16 + l16) * 40 + quad * 8];
                #pragma unroll
                for (int dt = 0; dt < 2; dt++)
                    oacc[mt][dt] = __builtin_amdgcn_mfma_f32_16x16x32_bf16(
                        pf, vf[dt], oacc[mt][dt], 0, 0, 0);
            }
        }
    }

    #pragma unroll
    for (int mt = 0; mt < 4; mt++)
        #pragma unroll
        for (int r = 0; r < 4; r++) {
            float l = lacc[mt][r];
            l += __shfl_xor(l, 1);
            l += __shfl_xor(l, 2);
            l += __shfl_xor(l, 4);
            l += __shfl_xor(l, 8);
            lacc[mt][r] = l;
        }

    #pragma unroll
    for (int mt = 0; mt < 4; mt++) {
        #pragma unroll
        for (int dt = 0; dt < 2; dt++) {
            #pragma unroll
            for (int r = 0; r < 4; r++) {
                float v = oacc[mt][dt][r] / lacc[mt][r];
                size_t node = (size_t)(g * NPG + qbase + mt * 16 + quad * 4 + r);
                attnout[node * HIDDEN + h * CDIM + dt * 16 + l16] = f2bf(v);
            }
        }
    }
}

// ---------------- GATv2 v2: 2 waves/node + software pipeline + fused LN1 ------
__device__ __forceinline__ void fetchmeta(
    int i, int re, int node, const int* __restrict__ col, const int* __restrict__ ei,
    const float* __restrict__ edge_attr, const float* __restrict__ ea_mean,
    int& s, float& a0, float& a1)
{
    if (i < re) {
        int e = col[i];
        if (e < E_EDGES) {
            s = ei[e]; a0 = edge_attr[2 * e]; a1 = edge_attr[2 * e + 1];
        } else {
            s = node; a0 = ea_mean[2 * node]; a1 = ea_mean[2 * node + 1];
        }
    } else {
        s = node; a0 = 0.f; a1 = 0.f;
    }
}

__global__ __launch_bounds__(256) void gat_kernel(
    const bf16* __restrict__ xlr,
    const int* __restrict__ row_ptr, const int* __restrict__ col,
    const int* __restrict__ ei, const float* __restrict__ edge_attr,
    const float* __restrict__ ea_mean,
    const float* __restrict__ W_e, const float* __restrict__ att,
    const float* __restrict__ bias_gat,
    const float* __restrict__ g1, const float* __restrict__ be1,
    bf16* __restrict__ out)
{
    __shared__ float pacc[2][260];
    __shared__ float plsum[2][64];
    int wave = threadIdx.x >> 6;
    int lane = threadIdx.x & 63;
    int nloc = wave >> 1, half = wave & 1;
    int node = blockIdx.x * 2 + nloc;
    int cb = lane * 4;

    float4 xr4 = load4(&xlr[(size_t)node * 512 + 256 + cb]);
    float4 we0 = *(const float4*)&W_e[cb];
    float4 we1 = *(const float4*)&W_e[HIDDEN + cb];
    float4 at4 = *(const float4*)&att[cb];

    int rs = row_ptr[node], re = row_ptr[node + 1];

    float lsum = 0.f;
    float acc0 = 0.f, acc1 = 0.f, acc2 = 0.f, acc3 = 0.f;

    int i0 = rs + half;
    int s0, s1; float a00, a01, a10, a11;
    fetchmeta(i0,     re, node, col, ei, edge_attr, ea_mean, s0, a00, a01);
    fetchmeta(i0 + 2, re, node, col, ei, edge_attr, ea_mean, s1, a10, a11);
    ushort4 xu0 = *(const ushort4*)&xlr[(size_t)s0 * 512 + cb];

    for (int i = i0; i < re; i += 2) {
        int s2; float a20, a21;
        fetchmeta(i + 4, re, node, col, ei, edge_attr, ea_mean, s2, a20, a21);
        ushort4 xu1 = *(const ushort4*)&xlr[(size_t)s1 * 512 + cb];

        float4 xl4 = make_float4(bf2f(xu0.x), bf2f(xu0.y), bf2f(xu0.z), bf2f(xu0.w));
        float t, p = 0.f;
        t = xl4.x + xr4.x + a00 * we0.x + a01 * we1.x; t = (t > 0.f) ? t : 0.2f * t; p += t * at4.x;
        t = xl4.y + xr4.y + a00 * we0.y + a01 * we1.y; t = (t > 0.f) ? t : 0.2f * t; p += t * at4.y;
        t = xl4.z + xr4.z + a00 * we0.z + a01 * we1.z; t = (t > 0.f) ? t : 0.2f * t; p += t * at4.z;
        t = xl4.w + xr4.w + a00 * we0.w + a01 * we1.w; t = (t > 0.f) ? t : 0.2f * t; p += t * at4.w;
        p += __shfl_xor(p, 1);
        p += __shfl_xor(p, 2);
        p += __shfl_xor(p, 4);
        float w = __expf(p);
        lsum += w;
        acc0 += w * xl4.x; acc1 += w * xl4.y; acc2 += w * xl4.z; acc3 += w * xl4.w;

        s0 = s1; a00 = a10; a01 = a11; xu0 = xu1;
        s1 = s2; a10 = a20; a11 = a21;
    }

    if (half) {
        plsum[nloc][lane] = lsum;
        pacc[nloc][cb + 0] = acc0; pacc[nloc][cb + 1] = acc1;
        pacc[nloc][cb + 2] = acc2; pacc[nloc][cb + 3] = acc3;
    }
    __syncthreads();
    if (!half) {
        lsum += plsum[nloc][lane];
        acc0 += pacc[nloc][cb + 0]; acc1 += pacc[nloc][cb + 1];
        acc2 += pacc[nloc][cb + 2]; acc3 += pacc[nloc][cb + 3];

        float inv = 1.0f / lsum;
        float v0 = acc0 * inv + bias_gat[cb + 0];
        float v1 = acc1 * inv + bias_gat[cb + 1];
        float v2 = acc2 * inv + bias_gat[cb + 2];
        float v3 = acc3 * inv + bias_gat[cb + 3];

        float s = v0 + v1 + v2 + v3;
        #pragma unroll
        for (int m = 1; m < 64; m <<= 1) s += __shfl_xor(s, m);
        float mean = s * (1.0f / 256.0f);
        float d0 = v0 - mean, d1 = v1 - mean, d2 = v2 - mean, d3 = v3 - mean;
        float sq = d0 * d0 + d1 * d1 + d2 * d2 + d3 * d3;
        #pragma unroll
        for (int m = 1; m < 64; m <<= 1) sq += __shfl_xor(sq, m);
        float rstd = rsqrtf(sq * (1.0f / 256.0f) + 1e-5f);
        float4 o;
        o.x = d0 * rstd * g1[cb + 0] + be1[cb + 0];
        o.y = d1 * rstd * g1[cb + 1] + be1[cb + 1];
        o.z = d2 * rstd * g1[cb + 2] + be1[cb + 2];
        o.w = d3 * rstd * g1[cb + 3] + be1[cb + 3];
        store4(&out[(size_t)node * HIDDEN + cb], o);
    }
}

// ---------------- LN2(gout) + gated combine ----------------
__global__ __launch_bounds__(256) void combine_kernel(
    const bf16* __restrict__ gout, const bf16* __restrict__ localout,
    const float* __restrict__ alpha_p,
    const float* __restrict__ g2, const float* __restrict__ be2,
    bf16* __restrict__ combined)
{
    int wave = threadIdx.x >> 6;
    int lane = threadIdx.x & 63;
    int node = blockIdx.x * 4 + wave;
    int cb = lane * 4;
    float4 gv = load4(&gout[(size_t)node * HIDDEN + cb]);
    float s = gv.x + gv.y + gv.z + gv.w;
    #pragma unroll
    for (int m = 1; m < 64; m <<= 1) s += __shfl_xor(s, m);
    float mean = s * (1.0f / 256.0f);
    float d0 = gv.x - mean, d1 = gv.y - mean, d2 = gv.z - mean, d3 = gv.w - mean;
    float sq = d0 * d0 + d1 * d1 + d2 * d2 + d3 * d3;
    #pragma unroll
    for (int m = 1; m < 64; m <<= 1) sq += __shfl_xor(sq, m);
    float rstd = rsqrtf(sq * (1.0f / 256.0f) + 1e-5f);
    float n0 = d0 * rstd * g2[cb + 0] + be2[cb + 0];
    float n1 = d1 * rstd * g2[cb + 1] + be2[cb + 1];
    float n2 = d2 * rstd * g2[cb + 2] + be2[cb + 2];
    float n3 = d3 * rstd * g2[cb + 3] + be2[cb + 3];
    float a = 1.0f / (1.0f + __expf(-alpha_p[0]));
    float4 lv = load4(&localout[(size_t)node * HIDDEN + cb]);
    float4 o;
    o.x = a * lv.x + (1.0f - a) * n0;
    o.y = a * lv.y + (1.0f - a) * n1;
    o.z = a * lv.z + (1.0f - a) * n2;
    o.w = a * lv.w + (1.0f - a) * n3;
    store4(&combined[(size_t)node * HIDDEN + cb], o);
}

// ---------------- final LN3 ----------------
__global__ __launch_bounds__(256) void finalln_kernel(
    const bf16* __restrict__ ffn,
    const float* __restrict__ g3, const float* __restrict__ be3,
    float* __restrict__ out)
{
    int wave = threadIdx.x >> 6;
    int lane = threadIdx.x & 63;
    int node = blockIdx.x * 4 + wave;
    int cb = lane * 4;
    float4 v = load4(&ffn[(size_t)node * HIDDEN + cb]);
    float s = v.x + v.y + v.z + v.w;
    #pragma unroll
    for (int m = 1; m < 64; m <<= 1) s += __shfl_xor(s, m);
    float mean = s * (1.0f / 256.0f);
    float d0 = v.x - mean, d1 = v.y - mean, d2 = v.z - mean, d3 = v.w - mean;
    float sq = d0 * d0 + d1 * d1 + d2 * d2 + d3 * d3;
    #pragma unroll
    for (int m = 1; m < 64; m <<= 1) sq += __shfl_xor(sq, m);
    float rstd = rsqrtf(sq * (1.0f / 256.0f) + 1e-5f);
    float4 o;
    o.x = d0 * rstd * g3[cb + 0] + be3[cb + 0];
    o.y = d1 * rstd * g3[cb + 1] + be3[cb + 1];
    o.z = d2 * rstd * g3[cb + 2] + be3[cb + 2];
    o.w = d3 * rstd * g3[cb + 3] + be3[cb + 3];
    *(float4*)&out[(size_t)node * HIDDEN + cb] = o;
}

// ---------------- launch ----------------
extern "C" void kernel_launch(void* const* d_in, const int* in_sizes, int n_in,
                              void* d_out, int out_size, void* d_ws, size_t ws_size,
                              hipStream_t stream) {
    const float* x          = (const float*)d_in[0];
    const float* edge_attr  = (const float*)d_in[1];
    const float* W_l        = (const float*)d_in[2];
    const float* b_l        = (const float*)d_in[3];
    const float* W_r        = (const float*)d_in[4];
    const float* b_r        = (const float*)d_in[5];
    const float* W_e        = (const float*)d_in[6];
    const float* att        = (const float*)d_in[7];
    const float* bias_gat   = (const float*)d_in[8];
    const float* in_proj_w  = (const float*)d_in[9];
    const float* in_proj_b  = (const float*)d_in[10];
    const float* out_proj_w = (const float*)d_in[11];
    const float* out_proj_b = (const float*)d_in[12];
    const float* alpha_p    = (const float*)d_in[13];
    const float* W1         = (const float*)d_in[14];
    const float* b1         = (const float*)d_in[15];
    const float* W2         = (const float*)d_in[16];
    const float* b2         = (const float*)d_in[17];
    const float* g1  = (const float*)d_in[18];
    const float* be1 = (const float*)d_in[19];
    const float* g2  = (const float*)d_in[20];
    const float* be2 = (const float*)d_in[21];
    const float* g3  = (const float*)d_in[22];
    const float* be3 = (const float*)d_in[23];
    const int* edge_index = (const int*)d_in[24];

    char* base = (char*)d_ws;
    const size_t MB = 1024 * 1024;
    const size_t KB = 1024;
    // graph prep [0, 3 MiB)
    float* deg     = (float*)(base + 0);
    float* ea_mean = (float*)(base + 131072);
    int*   fill    = (int*)  (base + 393216);
    int*   row_ptr = (int*)  (base + 524288);
    int*   col     = (int*)  (base + 786432);
    // bf16 weights [3 MiB, ~5 MiB)
    bf16* wlrb = (bf16*)(base + 3 * MB);              // 512x256  (256 KB)
    bf16* wipb = (bf16*)(base + 3 * MB + 256 * KB);   // 768x256  (384 KB)
    bf16* wopb = (bf16*)(base + 3 * MB + 640 * KB);   // 256x256  (128 KB)
    bf16* w1b  = (bf16*)(base + 3 * MB + 768 * KB);   // 1024x256 (512 KB)
    bf16* w2b  = (bf16*)(base + 3 * MB + 1280 * KB);  // 256x1024 (512 KB)
    float* blr = (float*)(base + 5 * MB);             // 512 floats
    // big bf16 buffers (aliased; peak 88 MiB)
    bf16* xb       = (bf16*)(base + 8 * MB);    // [8,24)
    bf16* qkv      = (bf16*)(base + 24 * MB);   // [24,72)
    bf16* attnout  = (bf16*)(base + 72 * MB);   // [72,88)
    bf16* gout     = (bf16*)(base + 24 * MB);   // [24,40)  (qkv dead)
    bf16* xlr      = (bf16*)(base + 40 * MB);   // [40,72)  (qkv dead)  [N][512]
    bf16* localout = (bf16*)(base + 72 * MB);   // [72,88)  (attnout dead)
    bf16* combined = (bf16*)(base + 8 * MB);    // [8,24)   (xb dead)
    bf16* h1h      = (bf16*)(base + 24 * MB);   // [24,56)  (gout/xlr-lower dead)
    bf16* ffn      = (bf16*)(base + 56 * MB);   // [56,72)  (xlr-upper dead)
    float* out = (float*)d_out;

    // ---- GAT graph prep ----
    zero_kernel<<<(2 * N_NODES + 255) / 256, 256, 0, stream>>>(deg, ea_mean, fill);
    deg_kernel<<<E_EDGES / 256, 256, 0, stream>>>(edge_index, edge_attr, deg, ea_mean);
    eamean_kernel<<<N_NODES / 256, 256, 0, stream>>>(deg, ea_mean);
    scan_kernel<<<1, 1024, 0, stream>>>(deg, row_ptr);
    fill_kernel<<<(E_EDGES + N_NODES) / 256, 256, 0, stream>>>(edge_index, row_ptr, fill, col);

    // ---- conversions (single launch) ----
    convall<<<11009, 256, 0, stream>>>(x, W_l, W_r, W1, W2, in_proj_w, out_proj_w,
                                       b_l, b_r, xb, wlrb, w1b, w2b, wipb, wopb, blr);

    // ---- MHA path first ----
    mfma_gemm<0><<<dim3(6, 256), 256, 0, stream>>>(
        xb, wipb, in_proj_b, (const bf16*)nullptr, qkv, N_NODES, 768, 256);
    attn_mfma<<<NGRAPH * NHEAD * 2, 256, 0, stream>>>(qkv, attnout);
    mfma_gemm<0><<<dim3(2, 256), 256, 0, stream>>>(
        attnout, wopb, out_proj_b, (const bf16*)nullptr, gout, N_NODES, 256, 256);

    // ---- GAT path (fused xl|xr GEMM, N=512) ----
    mfma_gemm<0><<<dim3(4, 256), 256, 0, stream>>>(
        xb, wlrb, blr, (const bf16*)nullptr, xlr, N_NODES, 512, 256);
    gat_kernel<<<N_NODES / 2, 256, 0, stream>>>(
        xlr, row_ptr, col, edge_index, edge_attr, ea_mean,
        W_e, att, bias_gat, g1, be1, localout);

    // ---- LN2 + gated combine ----
    combine_kernel<<<N_NODES / 4, 256, 0, stream>>>(
        gout, localout, alpha_p, g2, be2, combined);

    // ---- FFN in two M-halves ----
    for (int hh = 0; hh < 2; hh++) {
        const bf16* ch = combined + (size_t)hh * 16384 * 256;
        bf16* fh = ffn + (size_t)hh * 16384 * 256;
        mfma_gemm<1><<<dim3(8, 128), 256, 0, stream>>>(
            ch, w1b, b1, (const bf16*)nullptr, h1h, 16384, 1024, 256);
        mfma_gemm<2><<<dim3(2, 128), 256, 0, stream>>>(
            h1h, w2b, b2, ch, fh, 16384, 256, 1024);
    }

    // ---- LN3 -> out ----
    finalln_kernel<<<N_NODES / 4, 256, 0, stream>>>(ffn, g3, be3, out);
}